// Round 7
// baseline (101.384 us; speedup 1.0000x reference)
//
#include <hip/hip_runtime.h>

// Fixed problem geometry from setup_inputs(): X (32,512,512,8) f32, theta (32,6) f32
constexpr int B = 32;
constexpr int H = 512;
constexpr int W = 512;
constexpr int HW = H * W;          // 262144 = 2^18
constexpr int NXCD = 8;

// Native vector type: __builtin_nontemporal_store requires scalar/ext-vector.
typedef float f32x4 __attribute__((ext_vector_type(4)));

// TWO y-adjacent output pixels per thread; each 256-thread block covers a
// 64x8 pixel tile (4 thread-rows x 2 image rows each). Amortizes theta/decode
// and the shared t0*xg / t3*xg products, doubles gather MLP (16 outstanding
// loads), and captures the bilinear y-overlap in-register/L1.
//
// NUMERICS (hard-won): coordinate path AND blend both in f64.
//  - f32 coords flip floor/clip at the border discontinuities vs the numpy
//    f64 reference (round-1: absmax 0.094).
//  - f32 BLEND also fails (round-6: 0.09375 > 0.0875): the harness compares
//    ULP-wise against an f64 recompute; f32 blend rounding (~1e-7 rel) flips
//    thousands of outputs across rounding boundaries. Blend must track the
//    reference to f64 precision, then round once.
__global__ __launch_bounds__(256) void stn_bilinear_kernel(
    const f32x4* __restrict__ X4,      // X viewed as f32x4: 2 per pixel
    const float* __restrict__ theta,   // (B,6)
    f32x4*       __restrict__ out4)    // same layout as X4
{
    // Grid: 32 images x 64 tile-rows x 8 tile-cols = 16384 blocks.
    // XCD-aware bijective swizzle: contiguous chunks of 2048 blocks per XCD.
    const int nblk = 16384;
    const int cpx  = nblk / NXCD;                  // 2048
    const int bid  = (int)blockIdx.x;
    const int swz  = (bid % NXCD) * cpx + bid / NXCD;

    const int b    = swz >> 9;                     // / (8*64)
    const int rem  = swz & 511;
    const int ty   = rem >> 3;                     // tile row 0..63 (8 rows each)
    const int tx   = rem & 7;                      // tile col 0..7

    const int tid  = (int)threadIdx.x;
    const int r    = tid >> 6;                     // thread-row 0..3
    const int w    = (tx << 6) | (tid & 63);
    const int h0   = (ty << 3) | (r << 1);         // even; h0+1 <= 511 always

    const float* t = theta + b * 6;                // block-uniform
    const double t0 = (double)t[0], t1 = (double)t[1], t2 = (double)t[2];
    const double t3 = (double)t[3], t4 = (double)t[4], t5 = (double)t[5];

    // numpy linspace(-1,1,512) f64: i*delta + start, endpoint forced to stop
    const double step = 2.0 / 511.0;
    const double xg   = (w == W - 1) ? 1.0 : (double)w * step - 1.0;
    const double t0xg = t0 * xg;                   // shared by both pixels
    const double t3xg = t3 * xg;

    const int base = b << 18;

    int    pidx[2][4];
    double wgt[2][4];

    #pragma unroll
    for (int pp = 0; pp < 2; ++pp) {
        const int h = h0 + pp;
        const double yg = (h == H - 1) ? 1.0 : (double)h * step - 1.0;

        const double xt = (t0xg + t1 * yg) + t2;   // same order as np einsum
        const double yt = (t3xg + t4 * yg) + t5;

        const double x = (0.5 * (xt + 1.0)) * (double)W;
        const double y = (0.5 * (yt + 1.0)) * (double)H;

        int x0 = (int)floor(x);
        int y0 = (int)floor(y);
        int x1 = x0 + 1;
        int y1 = y0 + 1;
        x0 = min(max(x0, 0), W - 1);
        x1 = min(max(x1, 0), W - 1);
        y0 = min(max(y0, 0), H - 1);
        y1 = min(max(y1, 0), H - 1);

        // Weights from the CLIPPED coords (matches the reference exactly)
        wgt[pp][0] = ((double)x1 - x) * ((double)y1 - y);   // wa
        wgt[pp][1] = ((double)x1 - x) * (y - (double)y0);   // wb
        wgt[pp][2] = (x - (double)x0) * ((double)y1 - y);   // wc
        wgt[pp][3] = (x - (double)x0) * (y - (double)y0);   // wd

        pidx[pp][0] = ((base | (y0 << 9)) | x0) << 1;
        pidx[pp][1] = ((base | (y1 << 9)) | x0) << 1;
        pidx[pp][2] = ((base | (y0 << 9)) | x1) << 1;
        pidx[pp][3] = ((base | (y1 << 9)) | x1) << 1;
    }

    // Issue all 16 gathers (MLP); compiler schedules the waits late.
    f32x4 c0[2][4], c1[2][4];
    #pragma unroll
    for (int pp = 0; pp < 2; ++pp) {
        #pragma unroll
        for (int k = 0; k < 4; ++k) {
            c0[pp][k] = X4[pidx[pp][k]];
            c1[pp][k] = X4[pidx[pp][k] + 1];
        }
    }

    #pragma unroll
    for (int pp = 0; pp < 2; ++pp) {
        const double wa = wgt[pp][0], wb = wgt[pp][1], wc = wgt[pp][2], wd = wgt[pp][3];
        f32x4 o0, o1;
        #pragma unroll
        for (int j = 0; j < 4; ++j) {
            o0[j] = (float)(((wa * (double)c0[pp][0][j] + wb * (double)c0[pp][1][j])
                             + wc * (double)c0[pp][2][j]) + wd * (double)c0[pp][3][j]);
            o1[j] = (float)(((wa * (double)c1[pp][0][j] + wb * (double)c1[pp][1][j])
                             + wc * (double)c1[pp][2][j]) + wd * (double)c1[pp][3][j]);
        }
        const int oidx = ((base | ((h0 + pp) << 9)) | w) << 1;
        __builtin_nontemporal_store(o0, &out4[oidx + 0]);
        __builtin_nontemporal_store(o1, &out4[oidx + 1]);
    }
}

extern "C" void kernel_launch(void* const* d_in, const int* in_sizes, int n_in,
                              void* d_out, int out_size, void* d_ws, size_t ws_size,
                              hipStream_t stream) {
    const f32x4* X4    = (const f32x4*)d_in[0];
    const float* theta = (const float*)d_in[1];
    f32x4*       out4  = (f32x4*)d_out;

    stn_bilinear_kernel<<<16384, 256, 0, stream>>>(X4, theta, out4);
}

// Round 8
// 88.218 us; speedup vs baseline: 1.1492x; 1.1492x over previous
//
#include <hip/hip_runtime.h>

// Fixed problem geometry from setup_inputs(): X (32,512,512,8) f32, theta (32,6) f32
constexpr int B = 32;
constexpr int H = 512;
constexpr int W = 512;
constexpr int HW = H * W;          // 262144 = 2^18
constexpr int NXCD = 8;

// Native vector type: __builtin_nontemporal_store requires scalar/ext-vector.
typedef float f32x4 __attribute__((ext_vector_type(4)));

// One thread per output pixel; 256-thread block = 64x4 pixel tile (4 waves =
// 4 adjacent output rows -> bilinear y-overlap hits L1; round-5: 107->92 us.
// Round-7's 2px/thread variant regressed -> reverted).
//
// KEY ALGEBRA: the reference clamps x0,x1,y0,y1 AFTER computing them, then
// builds weights from the CLAMPED values. When x is out of [0,511), clamping
// makes x0==x1, so Ia==Ic, Ib==Id and (x1f-x)+(x-x0f) = 0 exactly -> the
// blend cancels to ~1e-16 (one f64 rounding). Same for y. So OOB pixels are
// EXACTLY ZERO (to f64 rounding) and need no gathers at all. In-bounds pixels
// need no clamps (pure bilinear).
//
// NUMERICS (hard-won): coordinate path AND blend both in f64, same op order
// as numpy. f32 coords flip floor/clip at the borders (round-1: 0.094 fail);
// f32 blend drifts ULP-wise off the f64 reference (round-6: 0.0938 fail).
__global__ __launch_bounds__(256) void stn_bilinear_kernel(
    const f32x4* __restrict__ X4,      // X viewed as f32x4: 2 per pixel
    const float* __restrict__ theta,   // (B,6)
    f32x4*       __restrict__ out4)    // same layout as X4
{
    // Grid: 32 images x 128 tile-rows x 8 tile-cols = 32768 blocks.
    // XCD-aware bijective swizzle: contiguous chunks of 4096 blocks per XCD.
    const int nblk = 32768;
    const int cpx  = nblk / NXCD;                  // 4096
    const int bid  = (int)blockIdx.x;
    const int swz  = (bid % NXCD) * cpx + bid / NXCD;

    const int b    = swz >> 10;                    // / (8*128)
    const int rem  = swz & 1023;
    const int ty   = rem >> 3;                     // tile row 0..127
    const int tx   = rem & 7;                      // tile col 0..7

    const int tid  = (int)threadIdx.x;
    const int h    = (ty << 2) | (tid >> 6);       // 4 rows per tile
    const int w    = (tx << 6) | (tid & 63);       // 64 px per row

    const float* t = theta + b * 6;                // block-uniform
    const double t0 = (double)t[0], t1 = (double)t[1], t2 = (double)t[2];
    const double t3 = (double)t[3], t4 = (double)t[4], t5 = (double)t[5];

    // numpy linspace(-1,1,512) f64: i*delta + start, endpoint forced to stop
    const double step = 2.0 / 511.0;
    const double xg = (w == W - 1) ? 1.0 : (double)w * step - 1.0;
    const double yg = (h == H - 1) ? 1.0 : (double)h * step - 1.0;

    const double xt = (t0 * xg + t1 * yg) + t2;
    const double yt = (t3 * xg + t4 * yg) + t5;

    const double x = (0.5 * (xt + 1.0)) * (double)W;
    const double y = (0.5 * (yt + 1.0)) * (double)H;

    const int base = b << 18;
    const int oidx = ((base | (h << 9)) | w) << 1;

    // In-bounds <=> floor(x) in [0,510] and floor(y) in [0,510]
    //            <=> x in [0,511) and y in [0,511).
    if (x >= 0.0 && x < 511.0 && y >= 0.0 && y < 511.0) {
        const int x0 = (int)x;                     // == floor, x >= 0
        const int y0 = (int)y;
        const double x0f = (double)x0, y0f = (double)y0;
        const double x1f = x0f + 1.0,  y1f = y0f + 1.0;

        const double wa = (x1f - x) * (y1f - y);
        const double wb = (x1f - x) * (y - y0f);
        const double wc = (x - x0f) * (y1f - y);
        const double wd = (x - x0f) * (y - y0f);

        const int pa = ((base | (y0 << 9)) | x0) << 1;          // f32x4 idx
        const int pb = pa + (1 << 10);                          // y0+1 row
        const int pc = pa + 2;                                  // x0+1
        const int pd = pb + 2;

        const f32x4 A0 = X4[pa],     B0 = X4[pb],     C0 = X4[pc],     D0 = X4[pd];
        const f32x4 A1 = X4[pa + 1], B1 = X4[pb + 1], C1 = X4[pc + 1], D1 = X4[pd + 1];

        f32x4 o0, o1;
        #pragma unroll
        for (int j = 0; j < 4; ++j) {
            o0[j] = (float)(((wa * (double)A0[j] + wb * (double)B0[j])
                             + wc * (double)C0[j]) + wd * (double)D0[j]);
            o1[j] = (float)(((wa * (double)A1[j] + wb * (double)B1[j])
                             + wc * (double)C1[j]) + wd * (double)D1[j]);
        }
        __builtin_nontemporal_store(o0, &out4[oidx + 0]);
        __builtin_nontemporal_store(o1, &out4[oidx + 1]);
    } else {
        const f32x4 z = {0.0f, 0.0f, 0.0f, 0.0f};
        __builtin_nontemporal_store(z, &out4[oidx + 0]);
        __builtin_nontemporal_store(z, &out4[oidx + 1]);
    }
}

extern "C" void kernel_launch(void* const* d_in, const int* in_sizes, int n_in,
                              void* d_out, int out_size, void* d_ws, size_t ws_size,
                              hipStream_t stream) {
    const f32x4* X4    = (const f32x4*)d_in[0];
    const float* theta = (const float*)d_in[1];
    f32x4*       out4  = (f32x4*)d_out;

    stn_bilinear_kernel<<<32768, 256, 0, stream>>>(X4, theta, out4);
}

// Round 9
// 86.589 us; speedup vs baseline: 1.1709x; 1.0188x over previous
//
#include <hip/hip_runtime.h>

// Fixed problem geometry from setup_inputs(): X (32,512,512,8) f32, theta (32,6) f32
constexpr int B = 32;
constexpr int H = 512;
constexpr int W = 512;
constexpr int HW = H * W;          // 262144 = 2^18
constexpr int NXCD = 8;

// Native vector type: __builtin_nontemporal_store requires scalar/ext-vector.
typedef float f32x4 __attribute__((ext_vector_type(4)));

// One thread per output pixel; 512-thread block = 64x8 pixel tile (8 waves).
// Round-8 evidence: OccupancyPercent pinned ~47% at both VGPR=24 and VGPR=36
// -> workgroup-per-CU cap, not registers. Bigger workgroup = more resident
// waves per CU = latency hiding for the 8-scattered-load + f64 chain.
// (64x4 tile @256 thr: 92 us; OOB short-circuit: 88 us.)
//
// KEY ALGEBRA: reference clamps x0,x1,y0,y1 then builds weights from the
// CLAMPED values; OOB (x not in [0,511) or y not in [0,511)) makes the blend
// cancel EXACTLY to ~1e-16 -> store zeros, skip all 8 gathers + blend.
// In-bounds needs no clamps at all.
//
// NUMERICS (hard-won): coordinate path AND blend both in f64, same op order
// as numpy. f32 coords flip floor/clip at the borders (round-1: 0.094 fail);
// f32 blend drifts ULP-wise off the f64 reference (round-6: 0.0938 fail).
__global__ __launch_bounds__(512) void stn_bilinear_kernel(
    const f32x4* __restrict__ X4,      // X viewed as f32x4: 2 per pixel
    const float* __restrict__ theta,   // (B,6)
    f32x4*       __restrict__ out4)    // same layout as X4
{
    // Grid: 32 images x 64 tile-rows x 8 tile-cols = 16384 blocks.
    // XCD-aware bijective swizzle: contiguous chunks of 2048 blocks per XCD.
    const int nblk = 16384;
    const int cpx  = nblk / NXCD;                  // 2048
    const int bid  = (int)blockIdx.x;
    const int swz  = (bid % NXCD) * cpx + bid / NXCD;

    const int b    = swz >> 9;                     // / (8*64)
    const int rem  = swz & 511;
    const int ty   = rem >> 3;                     // tile row 0..63
    const int tx   = rem & 7;                      // tile col 0..7

    const int tid  = (int)threadIdx.x;
    const int h    = (ty << 3) | (tid >> 6);       // 8 rows per tile
    const int w    = (tx << 6) | (tid & 63);       // 64 px per row

    const float* t = theta + b * 6;                // block-uniform
    const double t0 = (double)t[0], t1 = (double)t[1], t2 = (double)t[2];
    const double t3 = (double)t[3], t4 = (double)t[4], t5 = (double)t[5];

    // numpy linspace(-1,1,512) f64: i*delta + start, endpoint forced to stop
    const double step = 2.0 / 511.0;
    const double xg = (w == W - 1) ? 1.0 : (double)w * step - 1.0;
    const double yg = (h == H - 1) ? 1.0 : (double)h * step - 1.0;

    const double xt = (t0 * xg + t1 * yg) + t2;
    const double yt = (t3 * xg + t4 * yg) + t5;

    const double x = (0.5 * (xt + 1.0)) * (double)W;
    const double y = (0.5 * (yt + 1.0)) * (double)H;

    const int base = b << 18;
    const int oidx = ((base | (h << 9)) | w) << 1;

    // In-bounds <=> x in [0,511) and y in [0,511)  (then x1=x0+1, y1=y0+1).
    if (x >= 0.0 && x < 511.0 && y >= 0.0 && y < 511.0) {
        const int x0 = (int)x;                     // == floor, x >= 0
        const int y0 = (int)y;
        const double x0f = (double)x0, y0f = (double)y0;
        const double x1f = x0f + 1.0,  y1f = y0f + 1.0;

        const double wa = (x1f - x) * (y1f - y);
        const double wb = (x1f - x) * (y - y0f);
        const double wc = (x - x0f) * (y1f - y);
        const double wd = (x - x0f) * (y - y0f);

        const int pa = ((base | (y0 << 9)) | x0) << 1;          // f32x4 idx
        const int pb = pa + (1 << 10);                          // y0+1 row
        const int pc = pa + 2;                                  // x0+1
        const int pd = pb + 2;

        const f32x4 A0 = X4[pa],     B0 = X4[pb],     C0 = X4[pc],     D0 = X4[pd];
        const f32x4 A1 = X4[pa + 1], B1 = X4[pb + 1], C1 = X4[pc + 1], D1 = X4[pd + 1];

        f32x4 o0, o1;
        #pragma unroll
        for (int j = 0; j < 4; ++j) {
            o0[j] = (float)(((wa * (double)A0[j] + wb * (double)B0[j])
                             + wc * (double)C0[j]) + wd * (double)D0[j]);
            o1[j] = (float)(((wa * (double)A1[j] + wb * (double)B1[j])
                             + wc * (double)C1[j]) + wd * (double)D1[j]);
        }
        __builtin_nontemporal_store(o0, &out4[oidx + 0]);
        __builtin_nontemporal_store(o1, &out4[oidx + 1]);
    } else {
        const f32x4 z = {0.0f, 0.0f, 0.0f, 0.0f};
        __builtin_nontemporal_store(z, &out4[oidx + 0]);
        __builtin_nontemporal_store(z, &out4[oidx + 1]);
    }
}

extern "C" void kernel_launch(void* const* d_in, const int* in_sizes, int n_in,
                              void* d_out, int out_size, void* d_ws, size_t ws_size,
                              hipStream_t stream) {
    const f32x4* X4    = (const f32x4*)d_in[0];
    const float* theta = (const float*)d_in[1];
    f32x4*       out4  = (f32x4*)d_out;

    stn_bilinear_kernel<<<16384, 512, 0, stream>>>(X4, theta, out4);
}

// Round 10
// 85.494 us; speedup vs baseline: 1.1858x; 1.0128x over previous
//
#include <hip/hip_runtime.h>

// Fixed problem geometry from setup_inputs(): X (32,512,512,8) f32, theta (32,6) f32
constexpr int B = 32;
constexpr int H = 512;
constexpr int W = 512;
constexpr int HW = H * W;          // 262144 = 2^18
constexpr int NXCD = 8;

// Native vector type: __builtin_nontemporal_store requires scalar/ext-vector.
typedef float f32x4 __attribute__((ext_vector_type(4)));

// One thread per output pixel; 512-thread block = 64x8 pixel tile (8 waves).
//
// KEY ALGEBRA: reference clamps x0,x1,y0,y1 then builds weights from the
// CLAMPED values; OOB (x not in [0,511) or y not in [0,511)) makes the blend
// cancel EXACTLY (Ia==Ic etc., weights sum to 0) -> store zeros, skip all 8
// gathers + blend. In-bounds needs no clamps at all.
//
// NUMERICS (hard-won, 3 failures' worth):
//  - Coordinate path (linspace/affine/floor) must be f64: the sampler is
//    discontinuous at the clip lines; f32 coords flip floor decisions vs the
//    numpy-f64 reference (round-1: absmax 0.094).
//  - Round-6's f32-blend failure (0.09375) was CATASTROPHIC CANCELLATION on
//    OOB pixels (clamped weights ~1e6, exactly cancelling; f32 leaves
//    ~ulp(1e6)~0.25 residue) -- NOT in-bounds rounding. With the OOB
//    short-circuit, in-bounds weights are in [0,1] and an f32 blend errs by
//    ~1e-6 << 8.75e-2 threshold. So: f64 coords, f32 blend.
__global__ __launch_bounds__(512) void stn_bilinear_kernel(
    const f32x4* __restrict__ X4,      // X viewed as f32x4: 2 per pixel
    const float* __restrict__ theta,   // (B,6)
    f32x4*       __restrict__ out4)    // same layout as X4
{
    // Grid: 32 images x 64 tile-rows x 8 tile-cols = 16384 blocks.
    // XCD-aware bijective swizzle: contiguous chunks of 2048 blocks per XCD.
    const int nblk = 16384;
    const int cpx  = nblk / NXCD;                  // 2048
    const int bid  = (int)blockIdx.x;
    const int swz  = (bid % NXCD) * cpx + bid / NXCD;

    const int b    = swz >> 9;                     // / (8*64)
    const int rem  = swz & 511;
    const int ty   = rem >> 3;                     // tile row 0..63
    const int tx   = rem & 7;                      // tile col 0..7

    const int tid  = (int)threadIdx.x;
    const int h    = (ty << 3) | (tid >> 6);       // 8 rows per tile
    const int w    = (tx << 6) | (tid & 63);       // 64 px per row

    const float* t = theta + b * 6;                // block-uniform
    const double t0 = (double)t[0], t1 = (double)t[1], t2 = (double)t[2];
    const double t3 = (double)t[3], t4 = (double)t[4], t5 = (double)t[5];

    // numpy linspace(-1,1,512) f64: i*delta + start, endpoint forced to stop
    const double step = 2.0 / 511.0;
    const double xg = (w == W - 1) ? 1.0 : (double)w * step - 1.0;
    const double yg = (h == H - 1) ? 1.0 : (double)h * step - 1.0;

    const double xt = (t0 * xg + t1 * yg) + t2;
    const double yt = (t3 * xg + t4 * yg) + t5;

    const double x = (0.5 * (xt + 1.0)) * (double)W;
    const double y = (0.5 * (yt + 1.0)) * (double)H;

    const int base = b << 18;
    const int oidx = ((base | (h << 9)) | w) << 1;

    // In-bounds <=> x in [0,511) and y in [0,511)  (then x1=x0+1, y1=y0+1).
    if (x >= 0.0 && x < 511.0 && y >= 0.0 && y < 511.0) {
        const int x0 = (int)x;                     // == floor, x >= 0
        const int y0 = (int)y;

        // Edge deltas exact in f64, then one rounding to f32 each.
        const float fx1 = (float)(x - (double)x0); // in [0,1)
        const float fy1 = (float)(y - (double)y0);
        const float fx0 = (float)(((double)x0 + 1.0) - x);
        const float fy0 = (float)(((double)y0 + 1.0) - y);

        const float wa = fx0 * fy0;
        const float wb = fx0 * fy1;
        const float wc = fx1 * fy0;
        const float wd = fx1 * fy1;

        const int pa = ((base | (y0 << 9)) | x0) << 1;          // f32x4 idx
        const int pb = pa + (1 << 10);                          // y0+1 row
        const int pc = pa + 2;                                  // x0+1
        const int pd = pb + 2;

        const f32x4 A0 = X4[pa],     B0 = X4[pb],     C0 = X4[pc],     D0 = X4[pd];
        const f32x4 A1 = X4[pa + 1], B1 = X4[pb + 1], C1 = X4[pc + 1], D1 = X4[pd + 1];

        // Packed f32 blend (v_pk_fma_f32): in-bounds weights in [0,1],
        // error ~1e-6 against the f64 reference -> far under threshold.
        const f32x4 o0 = ((A0 * wa + B0 * wb) + C0 * wc) + D0 * wd;
        const f32x4 o1 = ((A1 * wa + B1 * wb) + C1 * wc) + D1 * wd;

        __builtin_nontemporal_store(o0, &out4[oidx + 0]);
        __builtin_nontemporal_store(o1, &out4[oidx + 1]);
    } else {
        const f32x4 z = {0.0f, 0.0f, 0.0f, 0.0f};
        __builtin_nontemporal_store(z, &out4[oidx + 0]);
        __builtin_nontemporal_store(z, &out4[oidx + 1]);
    }
}

extern "C" void kernel_launch(void* const* d_in, const int* in_sizes, int n_in,
                              void* d_out, int out_size, void* d_ws, size_t ws_size,
                              hipStream_t stream) {
    const f32x4* X4    = (const f32x4*)d_in[0];
    const float* theta = (const float*)d_in[1];
    f32x4*       out4  = (f32x4*)d_out;

    stn_bilinear_kernel<<<16384, 512, 0, stream>>>(X4, theta, out4);
}

// Round 11
// 83.595 us; speedup vs baseline: 1.2128x; 1.0227x over previous
//
#include <hip/hip_runtime.h>

// Fixed problem geometry from setup_inputs(): X (32,512,512,8) f32, theta (32,6) f32
constexpr int B = 32;
constexpr int H = 512;
constexpr int W = 512;
constexpr int HW = H * W;          // 262144 = 2^18

// Native vector type: __builtin_nontemporal_store requires scalar/ext-vector.
typedef float f32x4 __attribute__((ext_vector_type(4)));

// One thread per output pixel; 512-thread block = 64x8 pixel tile (8 waves,
// y-overlap of the bilinear quad captured in L1 within the block).
//
// NO XCD swizzle (round-11 change): input is L3-resident (FETCH ~43 MB), so
// XCD-L2 affinity buys nothing, while chunking 4 whole images per XCD caused
// load imbalance (per-image cost varies ~3x with the OOB fraction). Identity
// mapping round-robins consecutive blocks across XCDs -> fine-grained balance.
//
// KEY ALGEBRA: reference clamps x0,x1,y0,y1 then builds weights from the
// CLAMPED values; OOB (x not in [0,511) or y not in [0,511)) makes the blend
// cancel EXACTLY (Ia==Ic etc., weights sum to 0) -> store zeros, skip all 8
// gathers + blend. In-bounds needs no clamps at all.
//
// NUMERICS (hard-won, 3 failures' worth):
//  - Coordinate path (linspace/affine/floor) must be f64: the sampler is
//    discontinuous at the clip lines; f32 coords flip floor decisions vs the
//    numpy-f64 reference (round-1: absmax 0.094).
//  - Round-6's f32-blend failure (0.09375) was CATASTROPHIC CANCELLATION on
//    OOB pixels (clamped weights ~1e6, exactly cancelling; f32 leaves
//    ~ulp(1e6)~0.25 residue) -- NOT in-bounds rounding. With the OOB
//    short-circuit, in-bounds weights are in [0,1] and an f32 blend errs by
//    ~1e-6 << 8.75e-2 threshold. So: f64 coords, f32 blend.
__global__ __launch_bounds__(512) void stn_bilinear_kernel(
    const f32x4* __restrict__ X4,      // X viewed as f32x4: 2 per pixel
    const float* __restrict__ theta,   // (B,6)
    f32x4*       __restrict__ out4)    // same layout as X4
{
    // Grid: 32 images x 64 tile-rows x 8 tile-cols = 16384 blocks, identity.
    const int bid  = (int)blockIdx.x;

    const int b    = bid >> 9;                     // / (8*64)
    const int rem  = bid & 511;
    const int ty   = rem >> 3;                     // tile row 0..63
    const int tx   = rem & 7;                      // tile col 0..7

    const int tid  = (int)threadIdx.x;
    const int h    = (ty << 3) | (tid >> 6);       // 8 rows per tile
    const int w    = (tx << 6) | (tid & 63);       // 64 px per row

    const float* t = theta + b * 6;                // block-uniform
    const double t0 = (double)t[0], t1 = (double)t[1], t2 = (double)t[2];
    const double t3 = (double)t[3], t4 = (double)t[4], t5 = (double)t[5];

    // numpy linspace(-1,1,512) f64: i*delta + start, endpoint forced to stop
    const double step = 2.0 / 511.0;
    const double xg = (w == W - 1) ? 1.0 : (double)w * step - 1.0;
    const double yg = (h == H - 1) ? 1.0 : (double)h * step - 1.0;

    const double xt = (t0 * xg + t1 * yg) + t2;
    const double yt = (t3 * xg + t4 * yg) + t5;

    const double x = (0.5 * (xt + 1.0)) * (double)W;
    const double y = (0.5 * (yt + 1.0)) * (double)H;

    const int base = b << 18;
    const int oidx = ((base | (h << 9)) | w) << 1;

    // In-bounds <=> x in [0,511) and y in [0,511)  (then x1=x0+1, y1=y0+1).
    if (x >= 0.0 && x < 511.0 && y >= 0.0 && y < 511.0) {
        const int x0 = (int)x;                     // == floor, x >= 0
        const int y0 = (int)y;

        // Edge deltas exact in f64, then one rounding to f32 each.
        const float fx1 = (float)(x - (double)x0); // in [0,1)
        const float fy1 = (float)(y - (double)y0);
        const float fx0 = (float)(((double)x0 + 1.0) - x);
        const float fy0 = (float)(((double)y0 + 1.0) - y);

        const float wa = fx0 * fy0;
        const float wb = fx0 * fy1;
        const float wc = fx1 * fy0;
        const float wd = fx1 * fy1;

        const int pa = ((base | (y0 << 9)) | x0) << 1;          // f32x4 idx
        const int pb = pa + (1 << 10);                          // y0+1 row
        const int pc = pa + 2;                                  // x0+1
        const int pd = pb + 2;

        const f32x4 A0 = X4[pa],     B0 = X4[pb],     C0 = X4[pc],     D0 = X4[pd];
        const f32x4 A1 = X4[pa + 1], B1 = X4[pb + 1], C1 = X4[pc + 1], D1 = X4[pd + 1];

        // Packed f32 blend (v_pk_fma_f32): in-bounds weights in [0,1],
        // error ~1e-6 against the f64 reference -> far under threshold.
        const f32x4 o0 = ((A0 * wa + B0 * wb) + C0 * wc) + D0 * wd;
        const f32x4 o1 = ((A1 * wa + B1 * wb) + C1 * wc) + D1 * wd;

        __builtin_nontemporal_store(o0, &out4[oidx + 0]);
        __builtin_nontemporal_store(o1, &out4[oidx + 1]);
    } else {
        const f32x4 z = {0.0f, 0.0f, 0.0f, 0.0f};
        __builtin_nontemporal_store(z, &out4[oidx + 0]);
        __builtin_nontemporal_store(z, &out4[oidx + 1]);
    }
}

extern "C" void kernel_launch(void* const* d_in, const int* in_sizes, int n_in,
                              void* d_out, int out_size, void* d_ws, size_t ws_size,
                              hipStream_t stream) {
    const f32x4* X4    = (const f32x4*)d_in[0];
    const float* theta = (const float*)d_in[1];
    f32x4*       out4  = (f32x4*)d_out;

    stn_bilinear_kernel<<<16384, 512, 0, stream>>>(X4, theta, out4);
}

// Round 12
// 54.309 us; speedup vs baseline: 1.8668x; 1.5393x over previous
//
#include <hip/hip_runtime.h>

// Fixed problem geometry from setup_inputs(): X (32,512,512,8) f32, theta (32,6) f32
constexpr int B = 32;
constexpr int H = 512;
constexpr int W = 512;
constexpr int HW = H * W;          // 262144 = 2^18

// Native vector type: __builtin_nontemporal_store requires scalar/ext-vector.
typedef float f32x4 __attribute__((ext_vector_type(4)));

// CHANNEL-SPLIT mapping (round-12): TWO threads per pixel — lanes 2i,2i+1 are
// pixel i's channel halves. One corner-load instruction now covers a pixel's
// full 32 B contiguously (one 64 B L1 line when x0 even), eliminating the
// pa/pa+1 duplicate line-touches of the per-pixel mapping. Theory: the kernel
// is L1 line-service-bound (~240 line-services/wave ≈ 55 us/CU); this halves
// them. 4 loads/thread instead of 8.
//
// Block = 512 threads = 256 px = 64x4 pixel tile (8 waves; bilinear y-overlap
// across the 4 adjacent rows is captured in L1 within the block - round 5).
// Identity block map (round-11: XCD chunking caused image-level imbalance;
// input is L3-resident so XCD-L2 affinity buys nothing).
//
// KEY ALGEBRA: reference clamps x0,x1,y0,y1 then builds weights from the
// CLAMPED values; OOB (x not in [0,511) or y not in [0,511)) makes the blend
// cancel EXACTLY -> store zeros, skip gathers + blend (round 8).
//
// NUMERICS (hard-won): coordinate path f64 (f32 flips floor/clip at the
// border discontinuities vs the numpy-f64 ref: round-1 fail 0.094). Blend in
// f32 is safe ONLY because OOB pixels never enter it (round-6's 0.0938 fail
// was catastrophic cancellation of the huge clamped OOB weights in f32, not
// in-bounds rounding); in-bounds weights lie in [0,1], err ~1e-6 << 8.75e-2.
__global__ __launch_bounds__(512) void stn_bilinear_kernel(
    const f32x4* __restrict__ X4,      // X viewed as f32x4: 2 per pixel
    const float* __restrict__ theta,   // (B,6)
    f32x4*       __restrict__ out4)    // same layout as X4
{
    // Grid: 32 images x 128 tile-rows x 8 tile-cols = 32768 blocks, identity.
    const int bid  = (int)blockIdx.x;
    const int b    = bid >> 10;                    // / (8*128)
    const int rem  = bid & 1023;
    const int ty   = rem >> 3;                     // tile row 0..127
    const int tx   = rem & 7;                      // tile col 0..7

    const int tid  = (int)threadIdx.x;
    const int half = tid & 1;                      // channel half 0/1
    const int p    = tid >> 1;                     // pixel-in-block 0..255
    const int h    = (ty << 2) | (p >> 6);         // 4 rows per tile
    const int w    = (tx << 6) | (p & 63);         // 64 px per row

    const float* t = theta + b * 6;                // block-uniform
    const double t0 = (double)t[0], t1 = (double)t[1], t2 = (double)t[2];
    const double t3 = (double)t[3], t4 = (double)t[4], t5 = (double)t[5];

    // numpy linspace(-1,1,512) f64: i*delta + start, endpoint forced to stop
    const double step = 2.0 / 511.0;
    const double xg = (w == W - 1) ? 1.0 : (double)w * step - 1.0;
    const double yg = (h == H - 1) ? 1.0 : (double)h * step - 1.0;

    const double xt = (t0 * xg + t1 * yg) + t2;
    const double yt = (t3 * xg + t4 * yg) + t5;

    const double x = (0.5 * (xt + 1.0)) * (double)W;
    const double y = (0.5 * (yt + 1.0)) * (double)H;

    const int base = b << 18;
    const int oidx = (((base | (h << 9)) | w) << 1) + half;

    // In-bounds <=> x in [0,511) and y in [0,511)  (then x1=x0+1, y1=y0+1).
    if (x >= 0.0 && x < 511.0 && y >= 0.0 && y < 511.0) {
        const int x0 = (int)x;                     // == floor, x >= 0
        const int y0 = (int)y;

        // Edge deltas exact in f64, then one rounding to f32 each.
        const float fx1 = (float)(x - (double)x0); // in [0,1)
        const float fy1 = (float)(y - (double)y0);
        const float fx0 = (float)(((double)x0 + 1.0) - x);
        const float fy0 = (float)(((double)y0 + 1.0) - y);

        const float wa = fx0 * fy0;
        const float wb = fx0 * fy1;
        const float wc = fx1 * fy0;
        const float wd = fx1 * fy1;

        // One corner load per instruction covers the pixel-pair's 32 B.
        const int pa = ((((base | (y0 << 9)) | x0) << 1)) + half;   // f32x4 idx
        const int pb = pa + (1 << 10);                              // y0+1 row
        const int pc = pa + 2;                                      // x0+1
        const int pd = pb + 2;

        const f32x4 A = X4[pa], Bv = X4[pb], Cv = X4[pc], Dv = X4[pd];

        // Packed f32 blend: in-bounds weights in [0,1], err ~1e-6.
        const f32x4 o = ((A * wa + Bv * wb) + Cv * wc) + Dv * wd;

        __builtin_nontemporal_store(o, &out4[oidx]);
    } else {
        const f32x4 z = {0.0f, 0.0f, 0.0f, 0.0f};
        __builtin_nontemporal_store(z, &out4[oidx]);
    }
}

extern "C" void kernel_launch(void* const* d_in, const int* in_sizes, int n_in,
                              void* d_out, int out_size, void* d_ws, size_t ws_size,
                              hipStream_t stream) {
    const f32x4* X4    = (const f32x4*)d_in[0];
    const float* theta = (const float*)d_in[1];
    f32x4*       out4  = (f32x4*)d_out;

    stn_bilinear_kernel<<<32768, 512, 0, stream>>>(X4, theta, out4);
}